// Round 17
// baseline (640.769 us; speedup 1.0000x reference)
//
#include <hip/hip_runtime.h>
#include <hip/hip_bf16.h>
#include <math.h>

constexpr int NN  = 16384;
constexpr int DD  = 64;
constexpr int CC  = 128;
constexpr int OO  = 128;
constexpr int KP1 = 17;
constexpr int NT  = 256;             // 64-col tiles per row
constexpr int CAP = 256;             // candidate cap per row

typedef __attribute__((ext_vector_type(8))) short short8;
typedef __attribute__((ext_vector_type(4))) float floatx4;

__device__ __forceinline__ float bf2f(unsigned short u) {
    union { unsigned u; float f; } c; c.u = ((unsigned)u) << 16; return c.f;
}
__device__ __forceinline__ unsigned short f2bf(float f) {
    union { float f; unsigned u; } c; c.f = f;
    unsigned b = c.u;
    return (unsigned short)((b + 0x7FFFu + ((b >> 16) & 1u)) >> 16);
}

// ---------------------------------------------------------------------------
// znbF: fragment-major bf16 layout. For node n, channel c:
//   tile t = n>>4, lm = n&15, kt = c>>5, lk = (c>>3)&3, e = c&7, lane = lk*16+lm
//   znbF[ ((t*4 + kt)*64 + lane)*8 + e ]
//
// GEMM notes (rounds 1-9, MI355X): LDS staging / upfront loads / schedule
// reorders all neutral-to-worse; XCD swizzle = 14x FETCH blowup; supertile
// 128x256 triangle grid (symmetry, bit-identical acc both roles); 8 waves x
// (32x64) + launch_bounds(512,4) -> occ 33%. GEMM at its latency wall.
// Tail: R10 radix-thresh regressed; R11 coop gather +11us; R12 zn32 gather
// +39us; R13 rank 31->16 +33us; R15 coarse-64 thresh +110us (the O(256^2)
// rank loop was the elephant; NOTE coarse L is LOOSER, not tighter --
// candidates rose slightly -- but thresh cost dominated. Middle-128 is a
// net loss: +22us thresh vs ~-16us cand/topk2. Coarse stays.)
// R16: SAGE kernels widened to 256 threads (half-block per 4 nodes) --
// doubles in-flight edge-gather chains; per-(node,channel) summation order
// unchanged -> bit-identical.
// ---------------------------------------------------------------------------

// Supertile decode: bid -> (bx, s); per s, bx in [0, 2s+1]. Prefix s^2+s.
__device__ __forceinline__ void super_coords(int bid, int& bx, int& s) {
    s = (int)((sqrt(4.0 * (double)bid + 1.0) - 1.0) * 0.5);
    while (s * s + s > bid) --s;
    while ((s + 1) * (s + 1) + (s + 1) <= bid) ++s;
    bx = bid - (s * s + s);
}

// A-fragment load for a 32-row strip: 8 x 1KB, values identical to before.
__device__ __forceinline__ void load_af(const short8* __restrict__ fb,
                                        int arow0, int lane,
                                        short8 (&af)[4][2])
{
    const int ta0 = arow0 >> 4;
    #pragma unroll
    for (int mt = 0; mt < 2; mt++)
        #pragma unroll
        for (int kt = 0; kt < 4; kt++)
            af[kt][mt] = fb[((size_t)(ta0 + mt) * 4 + kt) * 64 + lane];
}

// B-stream + MFMA for one 32x64 output strip. Per-accumulator chain:
// kt = 0,1,2,3 ascending -> identical in k_simmax/k_cand -> bit-identical.
__device__ __forceinline__ void gemm_b(const short8* __restrict__ fb,
                                       int bcol0, int lane,
                                       const short8 (&af)[4][2],
                                       floatx4 (&acc)[2][4])
{
    const int tb0 = bcol0 >> 4;

    #pragma unroll
    for (int i = 0; i < 2; i++)
        #pragma unroll
        for (int j = 0; j < 4; j++) acc[i][j] = (floatx4){0.f, 0.f, 0.f, 0.f};

    #pragma unroll
    for (int nt = 0; nt < 4; nt++) {
        #pragma unroll
        for (int kt = 0; kt < 4; kt++) {
            short8 bf8 = fb[((size_t)(tb0 + nt) * 4 + kt) * 64 + lane];
            #pragma unroll
            for (int mt = 0; mt < 2; mt++)
                acc[mt][nt] = __builtin_amdgcn_mfma_f32_16x16x32_bf16(
                    af[kt][mt], bf8, acc[mt][nt], 0, 0, 0);
        }
    }
}

// ---------------------------------------------------------------------------
// Preprocess: 8 nodes/block, 128 threads (thread = channel), fp64 math.
// Emits z32, zn32, znbF; also initializes deg/ccnt/nbr for its 8 nodes.
// ---------------------------------------------------------------------------
__global__ __launch_bounds__(128)
void k_pre(const float* __restrict__ x_raw, const float* __restrict__ eps,
           const float* __restrict__ col_logit, const float* __restrict__ type_logit,
           const float* __restrict__ W_enc, const float* __restrict__ b_enc,
           const float* __restrict__ W_mu, const float* __restrict__ b_mu,
           const float* __restrict__ W_lv, const float* __restrict__ b_lv,
           float* __restrict__ z32, float* __restrict__ zn32,
           unsigned short* __restrict__ znbF,
           int* __restrict__ deg, int* __restrict__ ccnt, int* __restrict__ nbr)
{
    const int tid = threadIdx.x;
    const int n0  = blockIdx.x * 8;
    __shared__ double xg[8][DD];
    __shared__ double hs[8][CC];
    __shared__ double zs[8][CC];
    __shared__ double part[8][16];
    __shared__ double rs_s[8];
    __shared__ double gcol[DD];

    // Merged init for this block's 8 nodes.
    if (tid < 8) { deg[n0 + tid] = 0; ccnt[n0 + tid] = 0; }
    if (tid < 8 * KP1) {
        int n = n0 + tid / KP1;
        nbr[(size_t)n0 * KP1 + tid] = n;
    }

    if (tid < DD) {
        double l = (double)col_logit[tid];
        double s = 1.0 / (1.0 + exp(-l * 0.5));
        gcol[tid] = fmin(fmax(s * 1.2 - 0.1, 0.0), 1.0);
    }
    __syncthreads();

    #pragma unroll
    for (int rpt = 0; rpt < 4; rpt++) {
        int idx = tid + rpt * 128;
        int m = idx >> 6, d = idx & 63;
        xg[m][d] = (double)x_raw[(size_t)(n0 + m) * DD + d] * gcol[d];
    }
    __syncthreads();

    double tg;
    {
        double l = (double)type_logit[0];
        double s = 1.0 / (1.0 + exp(-l * 0.5));
        tg = fmin(fmax(s * 1.2 - 0.1, 0.0), 1.0);
    }

    double h[8];
    #pragma unroll
    for (int m = 0; m < 8; m++) h[m] = (double)b_enc[tid];
    for (int d = 0; d < DD; d++) {
        double w = (double)W_enc[d * CC + tid];
        #pragma unroll
        for (int m = 0; m < 8; m++) h[m] += xg[m][d] * w;
    }
    #pragma unroll
    for (int m = 0; m < 8; m++) hs[m][tid] = h[m] * tg;
    __syncthreads();

    double mu[8], lv[8];
    #pragma unroll
    for (int m = 0; m < 8; m++) { mu[m] = (double)b_mu[tid]; lv[m] = (double)b_lv[tid]; }
    for (int j = 0; j < CC; j++) {
        double wm = (double)W_mu[j * CC + tid];
        double wl = (double)W_lv[j * CC + tid];
        #pragma unroll
        for (int m = 0; m < 8; m++) { double hj = hs[m][j]; mu[m] += hj * wm; lv[m] += hj * wl; }
    }
    #pragma unroll
    for (int m = 0; m < 8; m++) {
        double l = fmin(fmax(lv[m], -10.0), 10.0);
        zs[m][tid] = mu[m] + (double)eps[(size_t)(n0 + m) * CC + tid] * exp(0.5 * l);
    }
    __syncthreads();

    {
        int m = tid >> 4, t = tid & 15;
        double s = 0.0;
        for (int c = t; c < CC; c += 16) { double z = zs[m][c]; s += z * z; }
        part[m][t] = s;
    }
    __syncthreads();
    if (tid < 8) {
        double s = 0.0;
        for (int t = 0; t < 16; t++) s += part[tid][t];
        rs_s[tid] = 1.0 / sqrt(s + 1e-12);
    }
    __syncthreads();

    const int c  = tid;
    const int kt = c >> 5, lk = (c >> 3) & 3, e = c & 7;
    #pragma unroll
    for (int m = 0; m < 8; m++) {
        int n = n0 + m;
        double z  = zs[m][tid];
        double zn = z * rs_s[m];
        size_t o  = (size_t)n * CC + tid;
        z32[o]  = (float)z;
        float znf = (float)zn;
        zn32[o] = znf;
        size_t fo = ((size_t)((n >> 4) * 4 + kt) * 64 + lk * 16 + (n & 15)) * 8 + e;
        znbF[fo] = f2bf(znf);
    }
}

// ---------------------------------------------------------------------------
// Pass 1: tile maxes, supertile grid, 8 waves x (32x64). Row maxes direct.
// Col maxes: even waves write 32-row partials to cmx[h][half][col]; ONE
// barrier; odd waves fmax-combine and write straight to global.
// ---------------------------------------------------------------------------
__global__ __launch_bounds__(512, 4)
void k_simmax(const unsigned short* __restrict__ znbF, float* __restrict__ simmax)
{
    __shared__ float cmx[2][2][128];     // [h][half][col]
    const short8* fb = (const short8*)znbF;
    const int tid  = threadIdx.x;
    const int lane = tid & 63;
    const int wv   = tid >> 6;           // 0..7
    int bx, s;
    super_coords(blockIdx.x, bx, s);
    const int am0  = bx * 128;
    const int rgr  = wv & 3;             // 32-row group
    const int ch   = wv >> 2;            // 64-col half
    const int mq   = rgr * 32;
    const int nq   = ch * 64;
    const int lm   = lane & 15;
    const int lk   = lane >> 4;
    const int half = rgr >> 1;

    short8 af[4][2];
    load_af(fb, am0 + mq, lane, af);

    #pragma unroll
    for (int h = 0; h < 2; h++) {
        const int by = 2 * s + h;
        if (by < bx) continue;           // block-uniform condition
        const int bn0 = by * 128;

        floatx4 acc[2][4];
        gemm_b(fb, bn0 + nq, lane, af, acc);

        // Row maxes: this wave's 64 cols for each of its 32 rows.
        #pragma unroll
        for (int mt = 0; mt < 2; mt++)
            #pragma unroll
            for (int rg = 0; rg < 4; rg++) {
                int m = mq + mt * 16 + lk * 4 + rg;
                float mx = acc[mt][0][rg];
                #pragma unroll
                for (int nt = 1; nt < 4; nt++) mx = fmaxf(mx, acc[mt][nt][rg]);
                #pragma unroll
                for (int ss = 1; ss < 16; ss <<= 1) mx = fmaxf(mx, __shfl_xor(mx, ss));
                if (lm == 0)
                    simmax[(size_t)(am0 + m) * NT + (by * 2 + ch)] = mx;
            }

        // Col partial maxes over this wave's 32 rows.
        float pmax[4];
        #pragma unroll
        for (int nt = 0; nt < 4; nt++) {
            float v = acc[0][nt][0];
            #pragma unroll
            for (int mt = 0; mt < 2; mt++)
                #pragma unroll
                for (int rg = 0; rg < 4; rg++) v = fmaxf(v, acc[mt][nt][rg]);
            v = fmaxf(v, __shfl_xor(v, 16));
            v = fmaxf(v, __shfl_xor(v, 32));
            pmax[nt] = v;
        }
        if ((rgr & 1) == 0 && lane < 16) {
            #pragma unroll
            for (int nt = 0; nt < 4; nt++)
                cmx[h][half][nq + nt * 16 + lm] = pmax[nt];
        }
        __syncthreads();
        if ((rgr & 1) == 1 && lane < 16) {
            #pragma unroll
            for (int nt = 0; nt < 4; nt++) {
                int ci = nq + nt * 16 + lm;
                float v = fmaxf(cmx[h][half][ci], pmax[nt]);
                simmax[(size_t)(bn0 + ci) * NT + (bx * 2 + half)] = v;
            }
        }
    }
}

// ---------------------------------------------------------------------------
// L[row] = 17th-largest 256-col tile max (rank 16 of 64 coarse maxes).
// Granularity-independent proof: <=16 elements exceed S17 => <=16 coarse
// tile maxes exceed S17 => L <= S17; coverage + >=17 candidates guaranteed.
// ---------------------------------------------------------------------------
__global__ __launch_bounds__(256)
void k_thresh(const float* __restrict__ simmax, float* __restrict__ Lrow)
{
    const int r = blockIdx.x;
    const int tid = threadIdx.x;
    __shared__ float smax[NT];
    __shared__ float cz[64];
    smax[tid] = simmax[(size_t)r * NT + tid];
    __syncthreads();
    if (tid < 64) {
        float4 w = ((const float4*)smax)[tid];
        cz[tid] = fmaxf(fmaxf(w.x, w.y), fmaxf(w.z, w.w));
    }
    __syncthreads();
    if (tid < 64) {
        float v = cz[tid];
        int rank = 0;
        for (int j = 0; j < 64; j++) {
            float w = cz[j];
            rank += (w > v || (w == v && j < tid)) ? 1 : 0;
        }
        if (rank == 16) Lrow[r] = v;
    }
}

// ---------------------------------------------------------------------------
// Pass 2: supertile grid, 8 waves x (32x64), bit-identical acc. Each element
// checked against L[row] AND, off-diagonal, against L[col].
// ---------------------------------------------------------------------------
__global__ __launch_bounds__(512, 4)
void k_cand(const unsigned short* __restrict__ znbF, const float* __restrict__ Lrow,
            int* __restrict__ ccnt, int* __restrict__ ccol)
{
    __shared__ float LshA[128], LshB[2][128];
    const short8* fb = (const short8*)znbF;
    const int tid  = threadIdx.x;
    const int lane = tid & 63;
    const int wv   = tid >> 6;
    int bx, s;
    super_coords(blockIdx.x, bx, s);
    const int am0  = bx * 128;
    const int rgr  = wv & 3;
    const int ch   = wv >> 2;
    const int mq   = rgr * 32;
    const int nq   = ch * 64;
    const int lm   = lane & 15;
    const int lk   = lane >> 4;

    if (tid < 128)      LshA[tid]          = Lrow[am0 + tid] - 1e-3f;
    else if (tid < 256) LshB[0][tid - 128] = Lrow[(2 * s) * 128 + (tid - 128)] - 1e-3f;
    else if (tid < 384) LshB[1][tid - 256] = Lrow[(2 * s + 1) * 128 + (tid - 256)] - 1e-3f;
    __syncthreads();

    short8 af[4][2];
    load_af(fb, am0 + mq, lane, af);

    #pragma unroll
    for (int h = 0; h < 2; h++) {
        const int by = 2 * s + h;
        if (by < bx) continue;           // block-uniform condition
        const int bn0 = by * 128;
        const int diag = (bx == by);

        floatx4 acc[2][4];
        gemm_b(fb, bn0 + nq, lane, af, acc);

        #pragma unroll
        for (int mt = 0; mt < 2; mt++)
            #pragma unroll
            for (int rg = 0; rg < 4; rg++) {
                int m = mq + mt * 16 + lk * 4 + rg;
                float Lr = LshA[m];
                int row = am0 + m;
                #pragma unroll
                for (int nt = 0; nt < 4; nt++) {
                    float v = acc[mt][nt][rg];
                    int lcol = nq + nt * 16 + lm;
                    if (v >= Lr) {
                        int p = atomicAdd(&ccnt[row], 1);
                        if (p < CAP) ccol[(size_t)row * CAP + p] = bn0 + lcol;
                    }
                    if (!diag && v >= LshB[h][lcol]) {
                        int coll = bn0 + lcol;
                        int p = atomicAdd(&ccnt[coll], 1);
                        if (p < CAP) ccol[(size_t)coll * CAP + p] = row;
                    }
                }
            }
    }
}

// ---------------------------------------------------------------------------
// Final: fp64-accumulated re-rank of all candidates -> exact top-17.
// zn32 rows (512B), fp64 accumulation, fixed summation order + index
// tiebreak. Cooperative gather: 4 lanes per candidate, shfl combine.
// ---------------------------------------------------------------------------
__global__ __launch_bounds__(256)
void k_topk2(const int* __restrict__ ccnt, const int* __restrict__ ccol,
             const float* __restrict__ zn32,
             int* __restrict__ nbr, int* __restrict__ deg)
{
    const int r = blockIdx.x;
    const int tid = threadIdx.x;
    __shared__ double q[CC];
    __shared__ double dv[CAP];
    __shared__ int    cs[CAP];

    int C = ccnt[r]; if (C > CAP) C = CAP;
    if (tid < CC)
        q[tid] = (double)zn32[(size_t)r * CC + tid];
    if (tid < C) {
        int cx = ccol[(size_t)r * CAP + tid];
        cs[tid] = ((unsigned)cx < (unsigned)NN) ? cx : r;
    }
    __syncthreads();

    const int c0  = tid >> 2;        // candidate within chunk
    const int sub = tid & 3;         // 32-channel slice
    for (int cc = c0; cc < C; cc += 64) {
        int cx = cs[cc];
        double s = 0.0;
        const float4* zr = (const float4*)(zn32 + (size_t)cx * CC) + sub * 8;
        #pragma unroll 4
        for (int k = 0; k < 8; k++) {
            float4 v = zr[k];
            s += q[sub * 32 + 4 * k]     * (double)v.x;
            s += q[sub * 32 + 4 * k + 1] * (double)v.y;
            s += q[sub * 32 + 4 * k + 2] * (double)v.z;
            s += q[sub * 32 + 4 * k + 3] * (double)v.w;
        }
        s += __shfl_down(s, 2);
        s += __shfl_down(s, 1);
        if (sub == 0) dv[cc] = s;
    }
    __syncthreads();

    if (tid < C) {
        double v = dv[tid]; int ix = cs[tid];
        int rank = 0;
        for (int j = 0; j < C; j++) {
            double w = dv[j];
            rank += (w > v || (w == v && cs[j] < ix)) ? 1 : 0;
        }
        if (rank < KP1) {
            nbr[(size_t)r * KP1 + rank] = ix;
            if (ix != r && (unsigned)ix < (unsigned)NN) atomicAdd(&deg[ix], 1);
        }
    }
}

// ---------------------------------------------------------------------------
// Scan: one block, shuffle-based, 2 barriers.
// ---------------------------------------------------------------------------
__global__ __launch_bounds__(256)
void k_scan(const int* __restrict__ deg, int* __restrict__ rp, int* __restrict__ wp)
{
    const int tid  = threadIdx.x;
    const int lane = tid & 63;
    const int wv   = tid >> 6;
    const int base = tid * 64;

    int v[64];
    int sum = 0;
    #pragma unroll
    for (int i = 0; i < 16; i++) {
        int4 t = *(const int4*)&deg[base + i * 4];
        v[i*4+0] = t.x; v[i*4+1] = t.y; v[i*4+2] = t.z; v[i*4+3] = t.w;
        sum += t.x + t.y + t.z + t.w;
    }

    int inc = sum;
    #pragma unroll
    for (int off2 = 1; off2 < 64; off2 <<= 1) {
        int o = __shfl_up(inc, off2);
        if (lane >= off2) inc += o;
    }

    __shared__ int wtot[4];
    if (lane == 63) wtot[wv] = inc;
    __syncthreads();
    int woff = 0;
    for (int w = 0; w < wv; w++) woff += wtot[w];

    int run = woff + inc - sum;
    #pragma unroll
    for (int i = 0; i < 64; i++) {
        wp[base + i] = run;
        run += v[i];
        rp[base + i + 1] = run;
    }
    if (tid == 0) rp[0] = 0;
}

__global__ __launch_bounds__(256)
void k_fill(const int* __restrict__ nbr, int* __restrict__ wp, int* __restrict__ es)
{
    int e = blockIdx.x * 256 + threadIdx.x;
    if (e >= NN * KP1) return;
    int i = e / KP1;
    int dst = nbr[e];
    if (dst != i && (unsigned)dst < (unsigned)NN) {
        int pos = atomicAdd(&wp[dst], 1);
        if ((unsigned)pos < (unsigned)(NN * KP1)) es[pos] = i;
    }
}

// ---------------------------------------------------------------------------
// Fused SAGE layer 1: mean-gather (CSR) + relu(z@Ws + mean@Wn + b) -> h1.
// R16: 256 threads (g = tid>>7 owns nodes g*4..g*4+3, channel = tid&127).
// Each (node,channel) still computed by ONE thread, t-ascending gather and
// j-ascending matmul -> bit-identical; 2x in-flight gather chains.
// ---------------------------------------------------------------------------
__global__ __launch_bounds__(256)
void k_sage1(const float* __restrict__ z, const int* __restrict__ rp,
             const int* __restrict__ es,
             const float* __restrict__ Ws, const float* __restrict__ Wn,
             const float* __restrict__ bias, float* __restrict__ out)
{
    __shared__ float as[8][CC], ms[8][CC];
    const int tid = threadIdx.x;
    const int c   = tid & 127;
    const int g   = tid >> 7;        // 0 or 1
    const int n0 = blockIdx.x * 8;

    #pragma unroll
    for (int mm = 0; mm < 4; mm++) {
        int m = g * 4 + mm;
        int n = n0 + m;
        as[m][c] = z[(size_t)n * CC + c];
        int b = rp[n], e2 = rp[n + 1];
        if (b < 0) b = 0;
        if (e2 > NN * KP1) e2 = NN * KP1;
        float acc = 0.f;
        int cnt = 0;
        for (int t = b; t < e2; t++) {
            int s = es[t];
            if ((unsigned)s < (unsigned)NN) { acc += z[(size_t)s * CC + c]; cnt++; }
        }
        ms[m][c] = acc / fmaxf((float)cnt, 1.0f);
    }
    __syncthreads();

    float acc[4];
    #pragma unroll
    for (int mm = 0; mm < 4; mm++) acc[mm] = bias[c];
    for (int j = 0; j < CC; j++) {
        float ws = Ws[j * CC + c], wn = Wn[j * CC + c];
        #pragma unroll
        for (int mm = 0; mm < 4; mm++) {
            int m = g * 4 + mm;
            acc[mm] += as[m][j] * ws + ms[m][j] * wn;
        }
    }
    #pragma unroll
    for (int mm = 0; mm < 4; mm++)
        out[(size_t)(n0 + g * 4 + mm) * CC + c] = fmaxf(acc[mm], 0.f);
}

// ---------------------------------------------------------------------------
// Fused SAGE layer 2 + head: mean-gather + relu(...) -> h2 (LDS) -> head.
// 256 threads, same half-block decomposition as k_sage1; bit-identical.
// ---------------------------------------------------------------------------
__global__ __launch_bounds__(256)
void k_sage2h(const float* __restrict__ h1, const int* __restrict__ rp,
              const int* __restrict__ es,
              const float* __restrict__ Ws, const float* __restrict__ Wn,
              const float* __restrict__ bias,
              const float* __restrict__ Wh, const float* __restrict__ bh,
              float* __restrict__ out)
{
    __shared__ float as[8][CC], ms[8][CC], hs[8][CC];
    const int tid = threadIdx.x;
    const int c   = tid & 127;
    const int g   = tid >> 7;
    const int n0 = blockIdx.x * 8;

    #pragma unroll
    for (int mm = 0; mm < 4; mm++) {
        int m = g * 4 + mm;
        int n = n0 + m;
        as[m][c] = h1[(size_t)n * CC + c];
        int b = rp[n], e2 = rp[n + 1];
        if (b < 0) b = 0;
        if (e2 > NN * KP1) e2 = NN * KP1;
        float acc = 0.f;
        int cnt = 0;
        for (int t = b; t < e2; t++) {
            int s = es[t];
            if ((unsigned)s < (unsigned)NN) { acc += h1[(size_t)s * CC + c]; cnt++; }
        }
        ms[m][c] = acc / fmaxf((float)cnt, 1.0f);
    }
    __syncthreads();

    float acc[4];
    #pragma unroll
    for (int mm = 0; mm < 4; mm++) acc[mm] = bias[c];
    for (int j = 0; j < CC; j++) {
        float ws = Ws[j * CC + c], wn = Wn[j * CC + c];
        #pragma unroll
        for (int mm = 0; mm < 4; mm++) {
            int m = g * 4 + mm;
            acc[mm] += as[m][j] * ws + ms[m][j] * wn;
        }
    }
    #pragma unroll
    for (int mm = 0; mm < 4; mm++) hs[g * 4 + mm][c] = fmaxf(acc[mm], 0.f);
    __syncthreads();

    float acc2[4];
    #pragma unroll
    for (int mm = 0; mm < 4; mm++) acc2[mm] = bh[c];
    for (int j = 0; j < CC; j++) {
        float w = Wh[j * OO + c];
        #pragma unroll
        for (int mm = 0; mm < 4; mm++)
            acc2[mm] += hs[g * 4 + mm][j] * w;
    }
    #pragma unroll
    for (int mm = 0; mm < 4; mm++)
        out[(size_t)(n0 + g * 4 + mm) * OO + c] = acc2[mm];
}

// ---------------------------------------------------------------------------
extern "C" void kernel_launch(void* const* d_in, const int* in_sizes, int n_in,
                              void* d_out, int out_size, void* d_ws, size_t ws_size,
                              hipStream_t stream)
{
    const float* x_raw      = (const float*)d_in[0];
    const float* eps        = (const float*)d_in[1];
    const float* col_logit  = (const float*)d_in[2];
    const float* type_logit = (const float*)d_in[3];
    const float* W_enc      = (const float*)d_in[4];
    const float* b_enc      = (const float*)d_in[5];
    const float* W_mu       = (const float*)d_in[6];
    const float* b_mu       = (const float*)d_in[7];
    const float* W_lv       = (const float*)d_in[8];
    const float* b_lv       = (const float*)d_in[9];
    const float* W_self1    = (const float*)d_in[10];
    const float* W_nbr1     = (const float*)d_in[11];
    const float* b1         = (const float*)d_in[12];
    const float* W_self2    = (const float*)d_in[13];
    const float* W_nbr2     = (const float*)d_in[14];
    const float* b2         = (const float*)d_in[15];
    const float* W_head     = (const float*)d_in[16];
    const float* b_head     = (const float*)d_in[17];
    float* out              = (float*)d_out;

    char* base = (char*)d_ws;
    size_t off = 0;
    auto alloc = [&](size_t bytes) { size_t o = off; off = (off + bytes + 255) & ~(size_t)255; return o; };

    const size_t MAT  = (size_t)NN * CC * 4;   // 8.39 MB

    float* z32    = (float*)(base + alloc(MAT));
    float* zn32   = (float*)(base + alloc(MAT));
    float* h1     = (float*)(base + alloc(MAT));
    unsigned short* znbF = (unsigned short*)(base + alloc((size_t)NN * CC * 2)); // 4.2 MB
    float* simmax = (float*)(base + alloc((size_t)NN * NT * 4));               // 16.8 MB
    float* Lrow   = (float*)(base + alloc((size_t)NN * 4));
    int*   ccnt   = (int*)(base + alloc((size_t)NN * 4));
    int*   ccol   = (int*)(base + alloc((size_t)NN * CAP * 4));                // 16.8 MB
    int*   nbr    = (int*)(base + alloc((size_t)NN * KP1 * 4));
    int*   deg    = (int*)(base + alloc((size_t)NN * 4));
    int*   rp     = (int*)(base + alloc((size_t)(NN + 1) * 4));
    int*   wp     = (int*)(base + alloc((size_t)NN * 4));
    int*   es     = (int*)(base + alloc((size_t)NN * KP1 * 4));

    k_pre<<<NN / 8, 128, 0, stream>>>(x_raw, eps, col_logit, type_logit,
                                      W_enc, b_enc, W_mu, b_mu, W_lv, b_lv,
                                      z32, zn32, znbF, deg, ccnt, nbr);

    const int NSUP = 64 * 64 + 64;             // 4160 supertile blocks
    k_simmax<<<NSUP, 512, 0, stream>>>(znbF, simmax);
    k_thresh<<<NN, 256, 0, stream>>>(simmax, Lrow);
    k_cand<<<NSUP, 512, 0, stream>>>(znbF, Lrow, ccnt, ccol);
    k_topk2<<<NN, 256, 0, stream>>>(ccnt, ccol, zn32, nbr, deg);

    k_scan<<<1, 256, 0, stream>>>(deg, rp, wp);
    int eb = (NN * KP1 + 255) / 256;
    k_fill<<<eb, 256, 0, stream>>>(nbr, wp, es);

    k_sage1<<<NN / 8, 256, 0, stream>>>(z32, rp, es, W_self1, W_nbr1, b1, h1);
    k_sage2h<<<NN / 8, 256, 0, stream>>>(h1, rp, es, W_self2, W_nbr2, b2,
                                         W_head, b_head, out);

    (void)in_sizes; (void)n_in; (void)out_size;
}

// Round 18
// 598.841 us; speedup vs baseline: 1.0700x; 1.0700x over previous
//
#include <hip/hip_runtime.h>
#include <hip/hip_bf16.h>
#include <math.h>

constexpr int NN  = 16384;
constexpr int DD  = 64;
constexpr int CC  = 128;
constexpr int OO  = 128;
constexpr int KP1 = 17;
constexpr int NT  = 256;             // 64-col tiles per row
constexpr int CAP = 256;             // candidate cap per row

typedef __attribute__((ext_vector_type(8))) short short8;
typedef __attribute__((ext_vector_type(4))) float floatx4;

__device__ __forceinline__ float bf2f(unsigned short u) {
    union { unsigned u; float f; } c; c.u = ((unsigned)u) << 16; return c.f;
}
__device__ __forceinline__ unsigned short f2bf(float f) {
    union { float f; unsigned u; } c; c.f = f;
    unsigned b = c.u;
    return (unsigned short)((b + 0x7FFFu + ((b >> 16) & 1u)) >> 16);
}

// ---------------------------------------------------------------------------
// znbF: fragment-major bf16 layout. For node n, channel c:
//   tile t = n>>4, lm = n&15, kt = c>>5, lk = (c>>3)&3, e = c&7, lane = lk*16+lm
//   znbF[ ((t*4 + kt)*64 + lane)*8 + e ]
//
// GEMM notes (rounds 1-9, MI355X): LDS staging / upfront loads / schedule
// reorders all neutral-to-worse; XCD swizzle = 14x FETCH blowup; supertile
// 128x256 triangle grid (symmetry, bit-identical acc both roles); 8 waves x
// (32x64) + launch_bounds(512,4) -> occ 33%. GEMM at its latency wall.
// Tail: R10 radix-thresh regressed; R11 coop gather +11us; R12 zn32 gather
// +39us; R13 rank 31->16 +33us; R15 coarse-64 thresh +110us.
// R16 REGRESSED (-45us): widening SAGE to 256 thr halved per-thread gather
// ILP (8 -> 4 chains) for no net in-flight gain. 128-thread SAGE restored.
// This source == R15-verified best (595.5 us).
// ---------------------------------------------------------------------------

// Supertile decode: bid -> (bx, s); per s, bx in [0, 2s+1]. Prefix s^2+s.
__device__ __forceinline__ void super_coords(int bid, int& bx, int& s) {
    s = (int)((sqrt(4.0 * (double)bid + 1.0) - 1.0) * 0.5);
    while (s * s + s > bid) --s;
    while ((s + 1) * (s + 1) + (s + 1) <= bid) ++s;
    bx = bid - (s * s + s);
}

// A-fragment load for a 32-row strip: 8 x 1KB, values identical to before.
__device__ __forceinline__ void load_af(const short8* __restrict__ fb,
                                        int arow0, int lane,
                                        short8 (&af)[4][2])
{
    const int ta0 = arow0 >> 4;
    #pragma unroll
    for (int mt = 0; mt < 2; mt++)
        #pragma unroll
        for (int kt = 0; kt < 4; kt++)
            af[kt][mt] = fb[((size_t)(ta0 + mt) * 4 + kt) * 64 + lane];
}

// B-stream + MFMA for one 32x64 output strip. Per-accumulator chain:
// kt = 0,1,2,3 ascending -> identical in k_simmax/k_cand -> bit-identical.
__device__ __forceinline__ void gemm_b(const short8* __restrict__ fb,
                                       int bcol0, int lane,
                                       const short8 (&af)[4][2],
                                       floatx4 (&acc)[2][4])
{
    const int tb0 = bcol0 >> 4;

    #pragma unroll
    for (int i = 0; i < 2; i++)
        #pragma unroll
        for (int j = 0; j < 4; j++) acc[i][j] = (floatx4){0.f, 0.f, 0.f, 0.f};

    #pragma unroll
    for (int nt = 0; nt < 4; nt++) {
        #pragma unroll
        for (int kt = 0; kt < 4; kt++) {
            short8 bf8 = fb[((size_t)(tb0 + nt) * 4 + kt) * 64 + lane];
            #pragma unroll
            for (int mt = 0; mt < 2; mt++)
                acc[mt][nt] = __builtin_amdgcn_mfma_f32_16x16x32_bf16(
                    af[kt][mt], bf8, acc[mt][nt], 0, 0, 0);
        }
    }
}

// ---------------------------------------------------------------------------
// Preprocess: 8 nodes/block, 128 threads (thread = channel), fp64 math.
// Emits z32, zn32, znbF; also initializes deg/ccnt/nbr for its 8 nodes.
// ---------------------------------------------------------------------------
__global__ __launch_bounds__(128)
void k_pre(const float* __restrict__ x_raw, const float* __restrict__ eps,
           const float* __restrict__ col_logit, const float* __restrict__ type_logit,
           const float* __restrict__ W_enc, const float* __restrict__ b_enc,
           const float* __restrict__ W_mu, const float* __restrict__ b_mu,
           const float* __restrict__ W_lv, const float* __restrict__ b_lv,
           float* __restrict__ z32, float* __restrict__ zn32,
           unsigned short* __restrict__ znbF,
           int* __restrict__ deg, int* __restrict__ ccnt, int* __restrict__ nbr)
{
    const int tid = threadIdx.x;
    const int n0  = blockIdx.x * 8;
    __shared__ double xg[8][DD];
    __shared__ double hs[8][CC];
    __shared__ double zs[8][CC];
    __shared__ double part[8][16];
    __shared__ double rs_s[8];
    __shared__ double gcol[DD];

    // Merged init for this block's 8 nodes.
    if (tid < 8) { deg[n0 + tid] = 0; ccnt[n0 + tid] = 0; }
    if (tid < 8 * KP1) {
        int n = n0 + tid / KP1;
        nbr[(size_t)n0 * KP1 + tid] = n;
    }

    if (tid < DD) {
        double l = (double)col_logit[tid];
        double s = 1.0 / (1.0 + exp(-l * 0.5));
        gcol[tid] = fmin(fmax(s * 1.2 - 0.1, 0.0), 1.0);
    }
    __syncthreads();

    #pragma unroll
    for (int rpt = 0; rpt < 4; rpt++) {
        int idx = tid + rpt * 128;
        int m = idx >> 6, d = idx & 63;
        xg[m][d] = (double)x_raw[(size_t)(n0 + m) * DD + d] * gcol[d];
    }
    __syncthreads();

    double tg;
    {
        double l = (double)type_logit[0];
        double s = 1.0 / (1.0 + exp(-l * 0.5));
        tg = fmin(fmax(s * 1.2 - 0.1, 0.0), 1.0);
    }

    double h[8];
    #pragma unroll
    for (int m = 0; m < 8; m++) h[m] = (double)b_enc[tid];
    for (int d = 0; d < DD; d++) {
        double w = (double)W_enc[d * CC + tid];
        #pragma unroll
        for (int m = 0; m < 8; m++) h[m] += xg[m][d] * w;
    }
    #pragma unroll
    for (int m = 0; m < 8; m++) hs[m][tid] = h[m] * tg;
    __syncthreads();

    double mu[8], lv[8];
    #pragma unroll
    for (int m = 0; m < 8; m++) { mu[m] = (double)b_mu[tid]; lv[m] = (double)b_lv[tid]; }
    for (int j = 0; j < CC; j++) {
        double wm = (double)W_mu[j * CC + tid];
        double wl = (double)W_lv[j * CC + tid];
        #pragma unroll
        for (int m = 0; m < 8; m++) { double hj = hs[m][j]; mu[m] += hj * wm; lv[m] += hj * wl; }
    }
    #pragma unroll
    for (int m = 0; m < 8; m++) {
        double l = fmin(fmax(lv[m], -10.0), 10.0);
        zs[m][tid] = mu[m] + (double)eps[(size_t)(n0 + m) * CC + tid] * exp(0.5 * l);
    }
    __syncthreads();

    {
        int m = tid >> 4, t = tid & 15;
        double s = 0.0;
        for (int c = t; c < CC; c += 16) { double z = zs[m][c]; s += z * z; }
        part[m][t] = s;
    }
    __syncthreads();
    if (tid < 8) {
        double s = 0.0;
        for (int t = 0; t < 16; t++) s += part[tid][t];
        rs_s[tid] = 1.0 / sqrt(s + 1e-12);
    }
    __syncthreads();

    const int c  = tid;
    const int kt = c >> 5, lk = (c >> 3) & 3, e = c & 7;
    #pragma unroll
    for (int m = 0; m < 8; m++) {
        int n = n0 + m;
        double z  = zs[m][tid];
        double zn = z * rs_s[m];
        size_t o  = (size_t)n * CC + tid;
        z32[o]  = (float)z;
        float znf = (float)zn;
        zn32[o] = znf;
        size_t fo = ((size_t)((n >> 4) * 4 + kt) * 64 + lk * 16 + (n & 15)) * 8 + e;
        znbF[fo] = f2bf(znf);
    }
}

// ---------------------------------------------------------------------------
// Pass 1: tile maxes, supertile grid, 8 waves x (32x64). Row maxes direct.
// Col maxes: even waves write 32-row partials to cmx[h][half][col]; ONE
// barrier; odd waves fmax-combine and write straight to global.
// ---------------------------------------------------------------------------
__global__ __launch_bounds__(512, 4)
void k_simmax(const unsigned short* __restrict__ znbF, float* __restrict__ simmax)
{
    __shared__ float cmx[2][2][128];     // [h][half][col]
    const short8* fb = (const short8*)znbF;
    const int tid  = threadIdx.x;
    const int lane = tid & 63;
    const int wv   = tid >> 6;           // 0..7
    int bx, s;
    super_coords(blockIdx.x, bx, s);
    const int am0  = bx * 128;
    const int rgr  = wv & 3;             // 32-row group
    const int ch   = wv >> 2;            // 64-col half
    const int mq   = rgr * 32;
    const int nq   = ch * 64;
    const int lm   = lane & 15;
    const int lk   = lane >> 4;
    const int half = rgr >> 1;

    short8 af[4][2];
    load_af(fb, am0 + mq, lane, af);

    #pragma unroll
    for (int h = 0; h < 2; h++) {
        const int by = 2 * s + h;
        if (by < bx) continue;           // block-uniform condition
        const int bn0 = by * 128;

        floatx4 acc[2][4];
        gemm_b(fb, bn0 + nq, lane, af, acc);

        // Row maxes: this wave's 64 cols for each of its 32 rows.
        #pragma unroll
        for (int mt = 0; mt < 2; mt++)
            #pragma unroll
            for (int rg = 0; rg < 4; rg++) {
                int m = mq + mt * 16 + lk * 4 + rg;
                float mx = acc[mt][0][rg];
                #pragma unroll
                for (int nt = 1; nt < 4; nt++) mx = fmaxf(mx, acc[mt][nt][rg]);
                #pragma unroll
                for (int ss = 1; ss < 16; ss <<= 1) mx = fmaxf(mx, __shfl_xor(mx, ss));
                if (lm == 0)
                    simmax[(size_t)(am0 + m) * NT + (by * 2 + ch)] = mx;
            }

        // Col partial maxes over this wave's 32 rows.
        float pmax[4];
        #pragma unroll
        for (int nt = 0; nt < 4; nt++) {
            float v = acc[0][nt][0];
            #pragma unroll
            for (int mt = 0; mt < 2; mt++)
                #pragma unroll
                for (int rg = 0; rg < 4; rg++) v = fmaxf(v, acc[mt][nt][rg]);
            v = fmaxf(v, __shfl_xor(v, 16));
            v = fmaxf(v, __shfl_xor(v, 32));
            pmax[nt] = v;
        }
        if ((rgr & 1) == 0 && lane < 16) {
            #pragma unroll
            for (int nt = 0; nt < 4; nt++)
                cmx[h][half][nq + nt * 16 + lm] = pmax[nt];
        }
        __syncthreads();
        if ((rgr & 1) == 1 && lane < 16) {
            #pragma unroll
            for (int nt = 0; nt < 4; nt++) {
                int ci = nq + nt * 16 + lm;
                float v = fmaxf(cmx[h][half][ci], pmax[nt]);
                simmax[(size_t)(bn0 + ci) * NT + (bx * 2 + half)] = v;
            }
        }
    }
}

// ---------------------------------------------------------------------------
// L[row] = 17th-largest 256-col tile max (rank 16 of 64 coarse maxes).
// Granularity-independent proof: <=16 elements exceed S17 => <=16 coarse
// tile maxes exceed S17 => L <= S17; coverage + >=17 candidates guaranteed.
// ---------------------------------------------------------------------------
__global__ __launch_bounds__(256)
void k_thresh(const float* __restrict__ simmax, float* __restrict__ Lrow)
{
    const int r = blockIdx.x;
    const int tid = threadIdx.x;
    __shared__ float smax[NT];
    __shared__ float cz[64];
    smax[tid] = simmax[(size_t)r * NT + tid];
    __syncthreads();
    if (tid < 64) {
        float4 w = ((const float4*)smax)[tid];
        cz[tid] = fmaxf(fmaxf(w.x, w.y), fmaxf(w.z, w.w));
    }
    __syncthreads();
    if (tid < 64) {
        float v = cz[tid];
        int rank = 0;
        for (int j = 0; j < 64; j++) {
            float w = cz[j];
            rank += (w > v || (w == v && j < tid)) ? 1 : 0;
        }
        if (rank == 16) Lrow[r] = v;
    }
}

// ---------------------------------------------------------------------------
// Pass 2: supertile grid, 8 waves x (32x64), bit-identical acc. Each element
// checked against L[row] AND, off-diagonal, against L[col].
// ---------------------------------------------------------------------------
__global__ __launch_bounds__(512, 4)
void k_cand(const unsigned short* __restrict__ znbF, const float* __restrict__ Lrow,
            int* __restrict__ ccnt, int* __restrict__ ccol)
{
    __shared__ float LshA[128], LshB[2][128];
    const short8* fb = (const short8*)znbF;
    const int tid  = threadIdx.x;
    const int lane = tid & 63;
    const int wv   = tid >> 6;
    int bx, s;
    super_coords(blockIdx.x, bx, s);
    const int am0  = bx * 128;
    const int rgr  = wv & 3;
    const int ch   = wv >> 2;
    const int mq   = rgr * 32;
    const int nq   = ch * 64;
    const int lm   = lane & 15;
    const int lk   = lane >> 4;

    if (tid < 128)      LshA[tid]          = Lrow[am0 + tid] - 1e-3f;
    else if (tid < 256) LshB[0][tid - 128] = Lrow[(2 * s) * 128 + (tid - 128)] - 1e-3f;
    else if (tid < 384) LshB[1][tid - 256] = Lrow[(2 * s + 1) * 128 + (tid - 256)] - 1e-3f;
    __syncthreads();

    short8 af[4][2];
    load_af(fb, am0 + mq, lane, af);

    #pragma unroll
    for (int h = 0; h < 2; h++) {
        const int by = 2 * s + h;
        if (by < bx) continue;           // block-uniform condition
        const int bn0 = by * 128;
        const int diag = (bx == by);

        floatx4 acc[2][4];
        gemm_b(fb, bn0 + nq, lane, af, acc);

        #pragma unroll
        for (int mt = 0; mt < 2; mt++)
            #pragma unroll
            for (int rg = 0; rg < 4; rg++) {
                int m = mq + mt * 16 + lk * 4 + rg;
                float Lr = LshA[m];
                int row = am0 + m;
                #pragma unroll
                for (int nt = 0; nt < 4; nt++) {
                    float v = acc[mt][nt][rg];
                    int lcol = nq + nt * 16 + lm;
                    if (v >= Lr) {
                        int p = atomicAdd(&ccnt[row], 1);
                        if (p < CAP) ccol[(size_t)row * CAP + p] = bn0 + lcol;
                    }
                    if (!diag && v >= LshB[h][lcol]) {
                        int coll = bn0 + lcol;
                        int p = atomicAdd(&ccnt[coll], 1);
                        if (p < CAP) ccol[(size_t)coll * CAP + p] = row;
                    }
                }
            }
    }
}

// ---------------------------------------------------------------------------
// Final: fp64-accumulated re-rank of all candidates -> exact top-17.
// zn32 rows (512B), fp64 accumulation, fixed summation order + index
// tiebreak. Cooperative gather: 4 lanes per candidate, shfl combine.
// ---------------------------------------------------------------------------
__global__ __launch_bounds__(256)
void k_topk2(const int* __restrict__ ccnt, const int* __restrict__ ccol,
             const float* __restrict__ zn32,
             int* __restrict__ nbr, int* __restrict__ deg)
{
    const int r = blockIdx.x;
    const int tid = threadIdx.x;
    __shared__ double q[CC];
    __shared__ double dv[CAP];
    __shared__ int    cs[CAP];

    int C = ccnt[r]; if (C > CAP) C = CAP;
    if (tid < CC)
        q[tid] = (double)zn32[(size_t)r * CC + tid];
    if (tid < C) {
        int cx = ccol[(size_t)r * CAP + tid];
        cs[tid] = ((unsigned)cx < (unsigned)NN) ? cx : r;
    }
    __syncthreads();

    const int c0  = tid >> 2;        // candidate within chunk
    const int sub = tid & 3;         // 32-channel slice
    for (int cc = c0; cc < C; cc += 64) {
        int cx = cs[cc];
        double s = 0.0;
        const float4* zr = (const float4*)(zn32 + (size_t)cx * CC) + sub * 8;
        #pragma unroll 4
        for (int k = 0; k < 8; k++) {
            float4 v = zr[k];
            s += q[sub * 32 + 4 * k]     * (double)v.x;
            s += q[sub * 32 + 4 * k + 1] * (double)v.y;
            s += q[sub * 32 + 4 * k + 2] * (double)v.z;
            s += q[sub * 32 + 4 * k + 3] * (double)v.w;
        }
        s += __shfl_down(s, 2);
        s += __shfl_down(s, 1);
        if (sub == 0) dv[cc] = s;
    }
    __syncthreads();

    if (tid < C) {
        double v = dv[tid]; int ix = cs[tid];
        int rank = 0;
        for (int j = 0; j < C; j++) {
            double w = dv[j];
            rank += (w > v || (w == v && cs[j] < ix)) ? 1 : 0;
        }
        if (rank < KP1) {
            nbr[(size_t)r * KP1 + rank] = ix;
            if (ix != r && (unsigned)ix < (unsigned)NN) atomicAdd(&deg[ix], 1);
        }
    }
}

// ---------------------------------------------------------------------------
// Scan: one block, shuffle-based, 2 barriers.
// ---------------------------------------------------------------------------
__global__ __launch_bounds__(256)
void k_scan(const int* __restrict__ deg, int* __restrict__ rp, int* __restrict__ wp)
{
    const int tid  = threadIdx.x;
    const int lane = tid & 63;
    const int wv   = tid >> 6;
    const int base = tid * 64;

    int v[64];
    int sum = 0;
    #pragma unroll
    for (int i = 0; i < 16; i++) {
        int4 t = *(const int4*)&deg[base + i * 4];
        v[i*4+0] = t.x; v[i*4+1] = t.y; v[i*4+2] = t.z; v[i*4+3] = t.w;
        sum += t.x + t.y + t.z + t.w;
    }

    int inc = sum;
    #pragma unroll
    for (int off2 = 1; off2 < 64; off2 <<= 1) {
        int o = __shfl_up(inc, off2);
        if (lane >= off2) inc += o;
    }

    __shared__ int wtot[4];
    if (lane == 63) wtot[wv] = inc;
    __syncthreads();
    int woff = 0;
    for (int w = 0; w < wv; w++) woff += wtot[w];

    int run = woff + inc - sum;
    #pragma unroll
    for (int i = 0; i < 64; i++) {
        wp[base + i] = run;
        run += v[i];
        rp[base + i + 1] = run;
    }
    if (tid == 0) rp[0] = 0;
}

__global__ __launch_bounds__(256)
void k_fill(const int* __restrict__ nbr, int* __restrict__ wp, int* __restrict__ es)
{
    int e = blockIdx.x * 256 + threadIdx.x;
    if (e >= NN * KP1) return;
    int i = e / KP1;
    int dst = nbr[e];
    if (dst != i && (unsigned)dst < (unsigned)NN) {
        int pos = atomicAdd(&wp[dst], 1);
        if ((unsigned)pos < (unsigned)(NN * KP1)) es[pos] = i;
    }
}

// ---------------------------------------------------------------------------
// Fused SAGE layer 1: mean-gather (CSR) + relu(z@Ws + mean@Wn + b) -> h1.
// 128 threads, 8 nodes/block: 8 independent gather chains per thread (ILP)
// -- the 256-thread variant regressed 45us (R16 post-mortem).
// ---------------------------------------------------------------------------
__global__ __launch_bounds__(128)
void k_sage1(const float* __restrict__ z, const int* __restrict__ rp,
             const int* __restrict__ es,
             const float* __restrict__ Ws, const float* __restrict__ Wn,
             const float* __restrict__ bias, float* __restrict__ out)
{
    __shared__ float as[8][CC], ms[8][CC];
    const int tid = threadIdx.x;
    const int n0 = blockIdx.x * 8;

    #pragma unroll
    for (int m = 0; m < 8; m++) {
        int n = n0 + m;
        as[m][tid] = z[(size_t)n * CC + tid];
        int b = rp[n], e2 = rp[n + 1];
        if (b < 0) b = 0;
        if (e2 > NN * KP1) e2 = NN * KP1;
        float acc = 0.f;
        int cnt = 0;
        for (int t = b; t < e2; t++) {
            int s = es[t];
            if ((unsigned)s < (unsigned)NN) { acc += z[(size_t)s * CC + tid]; cnt++; }
        }
        ms[m][tid] = acc / fmaxf((float)cnt, 1.0f);
    }
    __syncthreads();

    float acc[8];
    #pragma unroll
    for (int m = 0; m < 8; m++) acc[m] = bias[tid];
    for (int j = 0; j < CC; j++) {
        float ws = Ws[j * CC + tid], wn = Wn[j * CC + tid];
        #pragma unroll
        for (int m = 0; m < 8; m++) acc[m] += as[m][j] * ws + ms[m][j] * wn;
    }
    #pragma unroll
    for (int m = 0; m < 8; m++)
        out[(size_t)(n0 + m) * CC + tid] = fmaxf(acc[m], 0.f);
}

// ---------------------------------------------------------------------------
// Fused SAGE layer 2 + head: mean-gather + relu(...) -> h2 (LDS) -> head.
// ---------------------------------------------------------------------------
__global__ __launch_bounds__(128)
void k_sage2h(const float* __restrict__ h1, const int* __restrict__ rp,
              const int* __restrict__ es,
              const float* __restrict__ Ws, const float* __restrict__ Wn,
              const float* __restrict__ bias,
              const float* __restrict__ Wh, const float* __restrict__ bh,
              float* __restrict__ out)
{
    __shared__ float as[8][CC], ms[8][CC], hs[8][CC];
    const int tid = threadIdx.x;
    const int n0 = blockIdx.x * 8;

    #pragma unroll
    for (int m = 0; m < 8; m++) {
        int n = n0 + m;
        as[m][tid] = h1[(size_t)n * CC + tid];
        int b = rp[n], e2 = rp[n + 1];
        if (b < 0) b = 0;
        if (e2 > NN * KP1) e2 = NN * KP1;
        float acc = 0.f;
        int cnt = 0;
        for (int t = b; t < e2; t++) {
            int s = es[t];
            if ((unsigned)s < (unsigned)NN) { acc += h1[(size_t)s * CC + tid]; cnt++; }
        }
        ms[m][tid] = acc / fmaxf((float)cnt, 1.0f);
    }
    __syncthreads();

    float acc[8];
    #pragma unroll
    for (int m = 0; m < 8; m++) acc[m] = bias[tid];
    for (int j = 0; j < CC; j++) {
        float ws = Ws[j * CC + tid], wn = Wn[j * CC + tid];
        #pragma unroll
        for (int m = 0; m < 8; m++) acc[m] += as[m][j] * ws + ms[m][j] * wn;
    }
    #pragma unroll
    for (int m = 0; m < 8; m++) hs[m][tid] = fmaxf(acc[m], 0.f);
    __syncthreads();

    float acc2[8];
    #pragma unroll
    for (int m = 0; m < 8; m++) acc2[m] = bh[tid];
    for (int j = 0; j < CC; j++) {
        float w = Wh[j * OO + tid];
        #pragma unroll
        for (int m = 0; m < 8; m++) acc2[m] += hs[m][j] * w;
    }
    #pragma unroll
    for (int m = 0; m < 8; m++)
        out[(size_t)(n0 + m) * OO + tid] = acc2[m];
}

// ---------------------------------------------------------------------------
extern "C" void kernel_launch(void* const* d_in, const int* in_sizes, int n_in,
                              void* d_out, int out_size, void* d_ws, size_t ws_size,
                              hipStream_t stream)
{
    const float* x_raw      = (const float*)d_in[0];
    const float* eps        = (const float*)d_in[1];
    const float* col_logit  = (const float*)d_in[2];
    const float* type_logit = (const float*)d_in[3];
    const float* W_enc      = (const float*)d_in[4];
    const float* b_enc      = (const float*)d_in[5];
    const float* W_mu       = (const float*)d_in[6];
    const float* b_mu       = (const float*)d_in[7];
    const float* W_lv       = (const float*)d_in[8];
    const float* b_lv       = (const float*)d_in[9];
    const float* W_self1    = (const float*)d_in[10];
    const float* W_nbr1     = (const float*)d_in[11];
    const float* b1         = (const float*)d_in[12];
    const float* W_self2    = (const float*)d_in[13];
    const float* W_nbr2     = (const float*)d_in[14];
    const float* b2         = (const float*)d_in[15];
    const float* W_head     = (const float*)d_in[16];
    const float* b_head     = (const float*)d_in[17];
    float* out              = (float*)d_out;

    char* base = (char*)d_ws;
    size_t off = 0;
    auto alloc = [&](size_t bytes) { size_t o = off; off = (off + bytes + 255) & ~(size_t)255; return o; };

    const size_t MAT  = (size_t)NN * CC * 4;   // 8.39 MB

    float* z32    = (float*)(base + alloc(MAT));
    float* zn32   = (float*)(base + alloc(MAT));
    float* h1     = (float*)(base + alloc(MAT));
    unsigned short* znbF = (unsigned short*)(base + alloc((size_t)NN * CC * 2)); // 4.2 MB
    float* simmax = (float*)(base + alloc((size_t)NN * NT * 4));               // 16.8 MB
    float* Lrow   = (float*)(base + alloc((size_t)NN * 4));
    int*   ccnt   = (int*)(base + alloc((size_t)NN * 4));
    int*   ccol   = (int*)(base + alloc((size_t)NN * CAP * 4));                // 16.8 MB
    int*   nbr    = (int*)(base + alloc((size_t)NN * KP1 * 4));
    int*   deg    = (int*)(base + alloc((size_t)NN * 4));
    int*   rp     = (int*)(base + alloc((size_t)(NN + 1) * 4));
    int*   wp     = (int*)(base + alloc((size_t)NN * 4));
    int*   es     = (int*)(base + alloc((size_t)NN * KP1 * 4));

    k_pre<<<NN / 8, 128, 0, stream>>>(x_raw, eps, col_logit, type_logit,
                                      W_enc, b_enc, W_mu, b_mu, W_lv, b_lv,
                                      z32, zn32, znbF, deg, ccnt, nbr);

    const int NSUP = 64 * 64 + 64;             // 4160 supertile blocks
    k_simmax<<<NSUP, 512, 0, stream>>>(znbF, simmax);
    k_thresh<<<NN, 256, 0, stream>>>(simmax, Lrow);
    k_cand<<<NSUP, 512, 0, stream>>>(znbF, Lrow, ccnt, ccol);
    k_topk2<<<NN, 256, 0, stream>>>(ccnt, ccol, zn32, nbr, deg);

    k_scan<<<1, 256, 0, stream>>>(deg, rp, wp);
    int eb = (NN * KP1 + 255) / 256;
    k_fill<<<eb, 256, 0, stream>>>(nbr, wp, es);

    k_sage1<<<NN / 8, 128, 0, stream>>>(z32, rp, es, W_self1, W_nbr1, b1, h1);
    k_sage2h<<<NN / 8, 128, 0, stream>>>(h1, rp, es, W_self2, W_nbr2, b2,
                                         W_head, b_head, out);

    (void)in_sizes; (void)n_in; (void)out_size;
}

// Round 19
// 589.370 us; speedup vs baseline: 1.0872x; 1.0161x over previous
//
#include <hip/hip_runtime.h>
#include <hip/hip_bf16.h>
#include <math.h>

constexpr int NN  = 16384;
constexpr int DD  = 64;
constexpr int CC  = 128;
constexpr int OO  = 128;
constexpr int KP1 = 17;
constexpr int NT  = 256;             // 64-col tiles per row
constexpr int CAP = 256;             // candidate cap per row

typedef __attribute__((ext_vector_type(8))) short short8;
typedef __attribute__((ext_vector_type(4))) float floatx4;

__device__ __forceinline__ float bf2f(unsigned short u) {
    union { unsigned u; float f; } c; c.u = ((unsigned)u) << 16; return c.f;
}
__device__ __forceinline__ unsigned short f2bf(float f) {
    union { float f; unsigned u; } c; c.f = f;
    unsigned b = c.u;
    return (unsigned short)((b + 0x7FFFu + ((b >> 16) & 1u)) >> 16);
}

// ---------------------------------------------------------------------------
// znbF: fragment-major bf16 layout. For node n, channel c:
//   tile t = n>>4, lm = n&15, kt = c>>5, lk = (c>>3)&3, e = c&7, lane = lk*16+lm
//   znbF[ ((t*4 + kt)*64 + lane)*8 + e ]
//
// GEMM notes (rounds 1-9, MI355X): LDS staging / upfront loads / schedule
// reorders all neutral-to-worse; XCD swizzle = 14x FETCH blowup; supertile
// 128x256 triangle grid (symmetry, bit-identical acc both roles); 8 waves x
// (32x64) + launch_bounds(512,4) -> occ 33%. GEMM at its latency wall
// (~3.8x above the 38us L2-BW floor across 7 tested structures).
// Tail: R10 radix-thresh regressed; R11 coop gather +11us; R12 zn32 gather
// +39us; R13 rank 31->16 +33us; R15 coarse-64 thresh +110us; R16 regressed
// (256-thr SAGE halved per-thread gather ILP; 128-thr restored R17).
// R18: k_simmax h-loop de-barriered (col partials for both h in regs, one
// uniform barrier after the loop -> h=0/h=1 load streams overlap like
// k_cand's); k_thresh slimmed to 64 threads with direct float4 loads.
// Both exact-value-preserving.
// ---------------------------------------------------------------------------

// Supertile decode: bid -> (bx, s); per s, bx in [0, 2s+1]. Prefix s^2+s.
__device__ __forceinline__ void super_coords(int bid, int& bx, int& s) {
    s = (int)((sqrt(4.0 * (double)bid + 1.0) - 1.0) * 0.5);
    while (s * s + s > bid) --s;
    while ((s + 1) * (s + 1) + (s + 1) <= bid) ++s;
    bx = bid - (s * s + s);
}

// A-fragment load for a 32-row strip: 8 x 1KB, values identical to before.
__device__ __forceinline__ void load_af(const short8* __restrict__ fb,
                                        int arow0, int lane,
                                        short8 (&af)[4][2])
{
    const int ta0 = arow0 >> 4;
    #pragma unroll
    for (int mt = 0; mt < 2; mt++)
        #pragma unroll
        for (int kt = 0; kt < 4; kt++)
            af[kt][mt] = fb[((size_t)(ta0 + mt) * 4 + kt) * 64 + lane];
}

// B-stream + MFMA for one 32x64 output strip. Per-accumulator chain:
// kt = 0,1,2,3 ascending -> identical in k_simmax/k_cand -> bit-identical.
__device__ __forceinline__ void gemm_b(const short8* __restrict__ fb,
                                       int bcol0, int lane,
                                       const short8 (&af)[4][2],
                                       floatx4 (&acc)[2][4])
{
    const int tb0 = bcol0 >> 4;

    #pragma unroll
    for (int i = 0; i < 2; i++)
        #pragma unroll
        for (int j = 0; j < 4; j++) acc[i][j] = (floatx4){0.f, 0.f, 0.f, 0.f};

    #pragma unroll
    for (int nt = 0; nt < 4; nt++) {
        #pragma unroll
        for (int kt = 0; kt < 4; kt++) {
            short8 bf8 = fb[((size_t)(tb0 + nt) * 4 + kt) * 64 + lane];
            #pragma unroll
            for (int mt = 0; mt < 2; mt++)
                acc[mt][nt] = __builtin_amdgcn_mfma_f32_16x16x32_bf16(
                    af[kt][mt], bf8, acc[mt][nt], 0, 0, 0);
        }
    }
}

// ---------------------------------------------------------------------------
// Preprocess: 8 nodes/block, 128 threads (thread = channel), fp64 math.
// Emits z32, zn32, znbF; also initializes deg/ccnt/nbr for its 8 nodes.
// ---------------------------------------------------------------------------
__global__ __launch_bounds__(128)
void k_pre(const float* __restrict__ x_raw, const float* __restrict__ eps,
           const float* __restrict__ col_logit, const float* __restrict__ type_logit,
           const float* __restrict__ W_enc, const float* __restrict__ b_enc,
           const float* __restrict__ W_mu, const float* __restrict__ b_mu,
           const float* __restrict__ W_lv, const float* __restrict__ b_lv,
           float* __restrict__ z32, float* __restrict__ zn32,
           unsigned short* __restrict__ znbF,
           int* __restrict__ deg, int* __restrict__ ccnt, int* __restrict__ nbr)
{
    const int tid = threadIdx.x;
    const int n0  = blockIdx.x * 8;
    __shared__ double xg[8][DD];
    __shared__ double hs[8][CC];
    __shared__ double zs[8][CC];
    __shared__ double part[8][16];
    __shared__ double rs_s[8];
    __shared__ double gcol[DD];

    // Merged init for this block's 8 nodes.
    if (tid < 8) { deg[n0 + tid] = 0; ccnt[n0 + tid] = 0; }
    if (tid < 8 * KP1) {
        int n = n0 + tid / KP1;
        nbr[(size_t)n0 * KP1 + tid] = n;
    }

    if (tid < DD) {
        double l = (double)col_logit[tid];
        double s = 1.0 / (1.0 + exp(-l * 0.5));
        gcol[tid] = fmin(fmax(s * 1.2 - 0.1, 0.0), 1.0);
    }
    __syncthreads();

    #pragma unroll
    for (int rpt = 0; rpt < 4; rpt++) {
        int idx = tid + rpt * 128;
        int m = idx >> 6, d = idx & 63;
        xg[m][d] = (double)x_raw[(size_t)(n0 + m) * DD + d] * gcol[d];
    }
    __syncthreads();

    double tg;
    {
        double l = (double)type_logit[0];
        double s = 1.0 / (1.0 + exp(-l * 0.5));
        tg = fmin(fmax(s * 1.2 - 0.1, 0.0), 1.0);
    }

    double h[8];
    #pragma unroll
    for (int m = 0; m < 8; m++) h[m] = (double)b_enc[tid];
    for (int d = 0; d < DD; d++) {
        double w = (double)W_enc[d * CC + tid];
        #pragma unroll
        for (int m = 0; m < 8; m++) h[m] += xg[m][d] * w;
    }
    #pragma unroll
    for (int m = 0; m < 8; m++) hs[m][tid] = h[m] * tg;
    __syncthreads();

    double mu[8], lv[8];
    #pragma unroll
    for (int m = 0; m < 8; m++) { mu[m] = (double)b_mu[tid]; lv[m] = (double)b_lv[tid]; }
    for (int j = 0; j < CC; j++) {
        double wm = (double)W_mu[j * CC + tid];
        double wl = (double)W_lv[j * CC + tid];
        #pragma unroll
        for (int m = 0; m < 8; m++) { double hj = hs[m][j]; mu[m] += hj * wm; lv[m] += hj * wl; }
    }
    #pragma unroll
    for (int m = 0; m < 8; m++) {
        double l = fmin(fmax(lv[m], -10.0), 10.0);
        zs[m][tid] = mu[m] + (double)eps[(size_t)(n0 + m) * CC + tid] * exp(0.5 * l);
    }
    __syncthreads();

    {
        int m = tid >> 4, t = tid & 15;
        double s = 0.0;
        for (int c = t; c < CC; c += 16) { double z = zs[m][c]; s += z * z; }
        part[m][t] = s;
    }
    __syncthreads();
    if (tid < 8) {
        double s = 0.0;
        for (int t = 0; t < 16; t++) s += part[tid][t];
        rs_s[tid] = 1.0 / sqrt(s + 1e-12);
    }
    __syncthreads();

    const int c  = tid;
    const int kt = c >> 5, lk = (c >> 3) & 3, e = c & 7;
    #pragma unroll
    for (int m = 0; m < 8; m++) {
        int n = n0 + m;
        double z  = zs[m][tid];
        double zn = z * rs_s[m];
        size_t o  = (size_t)n * CC + tid;
        z32[o]  = (float)z;
        float znf = (float)zn;
        zn32[o] = znf;
        size_t fo = ((size_t)((n >> 4) * 4 + kt) * 64 + lk * 16 + (n & 15)) * 8 + e;
        znbF[fo] = f2bf(znf);
    }
}

// ---------------------------------------------------------------------------
// Pass 1: tile maxes, supertile grid, 8 waves x (32x64). Row maxes written
// inside the h loop (no barriers). Col partials for BOTH h kept in regs;
// ONE uniform barrier after the loop, then even-wave partial write +
// odd-wave combine/write. Exact same fmax values as R15; h=0/h=1 load
// streams now overlap (as k_cand's already did).
// ---------------------------------------------------------------------------
__global__ __launch_bounds__(512, 4)
void k_simmax(const unsigned short* __restrict__ znbF, float* __restrict__ simmax)
{
    __shared__ float cmx[2][2][128];     // [h][half][col]
    const short8* fb = (const short8*)znbF;
    const int tid  = threadIdx.x;
    const int lane = tid & 63;
    const int wv   = tid >> 6;           // 0..7
    int bx, s;
    super_coords(blockIdx.x, bx, s);
    const int am0  = bx * 128;
    const int rgr  = wv & 3;             // 32-row group
    const int ch   = wv >> 2;            // 64-col half
    const int mq   = rgr * 32;
    const int nq   = ch * 64;
    const int lm   = lane & 15;
    const int lk   = lane >> 4;
    const int half = rgr >> 1;

    short8 af[4][2];
    load_af(fb, am0 + mq, lane, af);

    float pmaxall[2][4];

    #pragma unroll
    for (int h = 0; h < 2; h++) {
        const int by = 2 * s + h;
        if (by < bx) continue;           // block-uniform condition
        const int bn0 = by * 128;

        floatx4 acc[2][4];
        gemm_b(fb, bn0 + nq, lane, af, acc);

        // Row maxes: this wave's 64 cols for each of its 32 rows.
        #pragma unroll
        for (int mt = 0; mt < 2; mt++)
            #pragma unroll
            for (int rg = 0; rg < 4; rg++) {
                int m = mq + mt * 16 + lk * 4 + rg;
                float mx = acc[mt][0][rg];
                #pragma unroll
                for (int nt = 1; nt < 4; nt++) mx = fmaxf(mx, acc[mt][nt][rg]);
                #pragma unroll
                for (int ss = 1; ss < 16; ss <<= 1) mx = fmaxf(mx, __shfl_xor(mx, ss));
                if (lm == 0)
                    simmax[(size_t)(am0 + m) * NT + (by * 2 + ch)] = mx;
            }

        // Col partial maxes over this wave's 32 rows -> registers.
        #pragma unroll
        for (int nt = 0; nt < 4; nt++) {
            float v = acc[0][nt][0];
            #pragma unroll
            for (int mt = 0; mt < 2; mt++)
                #pragma unroll
                for (int rg = 0; rg < 4; rg++) v = fmaxf(v, acc[mt][nt][rg]);
            v = fmaxf(v, __shfl_xor(v, 16));
            v = fmaxf(v, __shfl_xor(v, 32));
            pmaxall[h][nt] = v;
        }
    }

    // Deferred combine: even waves stage partials for each valid h.
    if ((rgr & 1) == 0 && lane < 16) {
        #pragma unroll
        for (int h = 0; h < 2; h++) {
            if (2 * s + h < bx) continue;
            #pragma unroll
            for (int nt = 0; nt < 4; nt++)
                cmx[h][half][nq + nt * 16 + lm] = pmaxall[h][nt];
        }
    }
    __syncthreads();
    if ((rgr & 1) == 1 && lane < 16) {
        #pragma unroll
        for (int h = 0; h < 2; h++) {
            const int by = 2 * s + h;
            if (by < bx) continue;
            const int bn0 = by * 128;
            #pragma unroll
            for (int nt = 0; nt < 4; nt++) {
                int ci = nq + nt * 16 + lm;
                float v = fmaxf(cmx[h][half][ci], pmaxall[h][nt]);
                simmax[(size_t)(bn0 + ci) * NT + (bx * 2 + half)] = v;
            }
        }
    }
}

// ---------------------------------------------------------------------------
// L[row] = 17th-largest 256-col tile max (rank 16 of 64 coarse maxes).
// Granularity-independent proof: <=16 elements exceed S17 => <=16 coarse
// tile maxes exceed S17 => L <= S17; coverage + >=17 candidates guaranteed.
// R18: 64 threads, direct float4 loads (same 16B grouping -> same maxes).
// ---------------------------------------------------------------------------
__global__ __launch_bounds__(64)
void k_thresh(const float* __restrict__ simmax, float* __restrict__ Lrow)
{
    const int r = blockIdx.x;
    const int tid = threadIdx.x;
    __shared__ float cz[64];
    float4 w = ((const float4*)(simmax + (size_t)r * NT))[tid];
    cz[tid] = fmaxf(fmaxf(w.x, w.y), fmaxf(w.z, w.w));
    __syncthreads();
    float v = cz[tid];
    int rank = 0;
    for (int j = 0; j < 64; j++) {
        float w2 = cz[j];
        rank += (w2 > v || (w2 == v && j < tid)) ? 1 : 0;
    }
    if (rank == 16) Lrow[r] = v;
}

// ---------------------------------------------------------------------------
// Pass 2: supertile grid, 8 waves x (32x64), bit-identical acc. Each element
// checked against L[row] AND, off-diagonal, against L[col].
// ---------------------------------------------------------------------------
__global__ __launch_bounds__(512, 4)
void k_cand(const unsigned short* __restrict__ znbF, const float* __restrict__ Lrow,
            int* __restrict__ ccnt, int* __restrict__ ccol)
{
    __shared__ float LshA[128], LshB[2][128];
    const short8* fb = (const short8*)znbF;
    const int tid  = threadIdx.x;
    const int lane = tid & 63;
    const int wv   = tid >> 6;
    int bx, s;
    super_coords(blockIdx.x, bx, s);
    const int am0  = bx * 128;
    const int rgr  = wv & 3;
    const int ch   = wv >> 2;
    const int mq   = rgr * 32;
    const int nq   = ch * 64;
    const int lm   = lane & 15;
    const int lk   = lane >> 4;

    if (tid < 128)      LshA[tid]          = Lrow[am0 + tid] - 1e-3f;
    else if (tid < 256) LshB[0][tid - 128] = Lrow[(2 * s) * 128 + (tid - 128)] - 1e-3f;
    else if (tid < 384) LshB[1][tid - 256] = Lrow[(2 * s + 1) * 128 + (tid - 256)] - 1e-3f;
    __syncthreads();

    short8 af[4][2];
    load_af(fb, am0 + mq, lane, af);

    #pragma unroll
    for (int h = 0; h < 2; h++) {
        const int by = 2 * s + h;
        if (by < bx) continue;           // block-uniform condition
        const int bn0 = by * 128;
        const int diag = (bx == by);

        floatx4 acc[2][4];
        gemm_b(fb, bn0 + nq, lane, af, acc);

        #pragma unroll
        for (int mt = 0; mt < 2; mt++)
            #pragma unroll
            for (int rg = 0; rg < 4; rg++) {
                int m = mq + mt * 16 + lk * 4 + rg;
                float Lr = LshA[m];
                int row = am0 + m;
                #pragma unroll
                for (int nt = 0; nt < 4; nt++) {
                    float v = acc[mt][nt][rg];
                    int lcol = nq + nt * 16 + lm;
                    if (v >= Lr) {
                        int p = atomicAdd(&ccnt[row], 1);
                        if (p < CAP) ccol[(size_t)row * CAP + p] = bn0 + lcol;
                    }
                    if (!diag && v >= LshB[h][lcol]) {
                        int coll = bn0 + lcol;
                        int p = atomicAdd(&ccnt[coll], 1);
                        if (p < CAP) ccol[(size_t)coll * CAP + p] = row;
                    }
                }
            }
    }
}

// ---------------------------------------------------------------------------
// Final: fp64-accumulated re-rank of all candidates -> exact top-17.
// zn32 rows (512B), fp64 accumulation, fixed summation order + index
// tiebreak. Cooperative gather: 4 lanes per candidate, shfl combine.
// ---------------------------------------------------------------------------
__global__ __launch_bounds__(256)
void k_topk2(const int* __restrict__ ccnt, const int* __restrict__ ccol,
             const float* __restrict__ zn32,
             int* __restrict__ nbr, int* __restrict__ deg)
{
    const int r = blockIdx.x;
    const int tid = threadIdx.x;
    __shared__ double q[CC];
    __shared__ double dv[CAP];
    __shared__ int    cs[CAP];

    int C = ccnt[r]; if (C > CAP) C = CAP;
    if (tid < CC)
        q[tid] = (double)zn32[(size_t)r * CC + tid];
    if (tid < C) {
        int cx = ccol[(size_t)r * CAP + tid];
        cs[tid] = ((unsigned)cx < (unsigned)NN) ? cx : r;
    }
    __syncthreads();

    const int c0  = tid >> 2;        // candidate within chunk
    const int sub = tid & 3;         // 32-channel slice
    for (int cc = c0; cc < C; cc += 64) {
        int cx = cs[cc];
        double s = 0.0;
        const float4* zr = (const float4*)(zn32 + (size_t)cx * CC) + sub * 8;
        #pragma unroll 4
        for (int k = 0; k < 8; k++) {
            float4 v = zr[k];
            s += q[sub * 32 + 4 * k]     * (double)v.x;
            s += q[sub * 32 + 4 * k + 1] * (double)v.y;
            s += q[sub * 32 + 4 * k + 2] * (double)v.z;
            s += q[sub * 32 + 4 * k + 3] * (double)v.w;
        }
        s += __shfl_down(s, 2);
        s += __shfl_down(s, 1);
        if (sub == 0) dv[cc] = s;
    }
    __syncthreads();

    if (tid < C) {
        double v = dv[tid]; int ix = cs[tid];
        int rank = 0;
        for (int j = 0; j < C; j++) {
            double w = dv[j];
            rank += (w > v || (w == v && cs[j] < ix)) ? 1 : 0;
        }
        if (rank < KP1) {
            nbr[(size_t)r * KP1 + rank] = ix;
            if (ix != r && (unsigned)ix < (unsigned)NN) atomicAdd(&deg[ix], 1);
        }
    }
}

// ---------------------------------------------------------------------------
// Scan: one block, shuffle-based, 2 barriers.
// ---------------------------------------------------------------------------
__global__ __launch_bounds__(256)
void k_scan(const int* __restrict__ deg, int* __restrict__ rp, int* __restrict__ wp)
{
    const int tid  = threadIdx.x;
    const int lane = tid & 63;
    const int wv   = tid >> 6;
    const int base = tid * 64;

    int v[64];
    int sum = 0;
    #pragma unroll
    for (int i = 0; i < 16; i++) {
        int4 t = *(const int4*)&deg[base + i * 4];
        v[i*4+0] = t.x; v[i*4+1] = t.y; v[i*4+2] = t.z; v[i*4+3] = t.w;
        sum += t.x + t.y + t.z + t.w;
    }

    int inc = sum;
    #pragma unroll
    for (int off2 = 1; off2 < 64; off2 <<= 1) {
        int o = __shfl_up(inc, off2);
        if (lane >= off2) inc += o;
    }

    __shared__ int wtot[4];
    if (lane == 63) wtot[wv] = inc;
    __syncthreads();
    int woff = 0;
    for (int w = 0; w < wv; w++) woff += wtot[w];

    int run = woff + inc - sum;
    #pragma unroll
    for (int i = 0; i < 64; i++) {
        wp[base + i] = run;
        run += v[i];
        rp[base + i + 1] = run;
    }
    if (tid == 0) rp[0] = 0;
}

__global__ __launch_bounds__(256)
void k_fill(const int* __restrict__ nbr, int* __restrict__ wp, int* __restrict__ es)
{
    int e = blockIdx.x * 256 + threadIdx.x;
    if (e >= NN * KP1) return;
    int i = e / KP1;
    int dst = nbr[e];
    if (dst != i && (unsigned)dst < (unsigned)NN) {
        int pos = atomicAdd(&wp[dst], 1);
        if ((unsigned)pos < (unsigned)(NN * KP1)) es[pos] = i;
    }
}

// ---------------------------------------------------------------------------
// Fused SAGE layer 1: mean-gather (CSR) + relu(z@Ws + mean@Wn + b) -> h1.
// 128 threads, 8 nodes/block: 8 independent gather chains per thread (ILP)
// -- the 256-thread variant regressed 45us (R16 post-mortem).
// ---------------------------------------------------------------------------
__global__ __launch_bounds__(128)
void k_sage1(const float* __restrict__ z, const int* __restrict__ rp,
             const int* __restrict__ es,
             const float* __restrict__ Ws, const float* __restrict__ Wn,
             const float* __restrict__ bias, float* __restrict__ out)
{
    __shared__ float as[8][CC], ms[8][CC];
    const int tid = threadIdx.x;
    const int n0 = blockIdx.x * 8;

    #pragma unroll
    for (int m = 0; m < 8; m++) {
        int n = n0 + m;
        as[m][tid] = z[(size_t)n * CC + tid];
        int b = rp[n], e2 = rp[n + 1];
        if (b < 0) b = 0;
        if (e2 > NN * KP1) e2 = NN * KP1;
        float acc = 0.f;
        int cnt = 0;
        for (int t = b; t < e2; t++) {
            int s = es[t];
            if ((unsigned)s < (unsigned)NN) { acc += z[(size_t)s * CC + tid]; cnt++; }
        }
        ms[m][tid] = acc / fmaxf((float)cnt, 1.0f);
    }
    __syncthreads();

    float acc[8];
    #pragma unroll
    for (int m = 0; m < 8; m++) acc[m] = bias[tid];
    for (int j = 0; j < CC; j++) {
        float ws = Ws[j * CC + tid], wn = Wn[j * CC + tid];
        #pragma unroll
        for (int m = 0; m < 8; m++) acc[m] += as[m][j] * ws + ms[m][j] * wn;
    }
    #pragma unroll
    for (int m = 0; m < 8; m++)
        out[(size_t)(n0 + m) * CC + tid] = fmaxf(acc[m], 0.f);
}

// ---------------------------------------------------------------------------
// Fused SAGE layer 2 + head: mean-gather + relu(...) -> h2 (LDS) -> head.
// ---------------------------------------------------------------------------
__global__ __launch_bounds__(128)
void k_sage2h(const float* __restrict__ h1, const int* __restrict__ rp,
              const int* __restrict__ es,
              const float* __restrict__ Ws, const float* __restrict__ Wn,
              const float* __restrict__ bias,
              const float* __restrict__ Wh, const float* __restrict__ bh,
              float* __restrict__ out)
{
    __shared__ float as[8][CC], ms[8][CC], hs[8][CC];
    const int tid = threadIdx.x;
    const int n0 = blockIdx.x * 8;

    #pragma unroll
    for (int m = 0; m < 8; m++) {
        int n = n0 + m;
        as[m][tid] = h1[(size_t)n * CC + tid];
        int b = rp[n], e2 = rp[n + 1];
        if (b < 0) b = 0;
        if (e2 > NN * KP1) e2 = NN * KP1;
        float acc = 0.f;
        int cnt = 0;
        for (int t = b; t < e2; t++) {
            int s = es[t];
            if ((unsigned)s < (unsigned)NN) { acc += h1[(size_t)s * CC + tid]; cnt++; }
        }
        ms[m][tid] = acc / fmaxf((float)cnt, 1.0f);
    }
    __syncthreads();

    float acc[8];
    #pragma unroll
    for (int m = 0; m < 8; m++) acc[m] = bias[tid];
    for (int j = 0; j < CC; j++) {
        float ws = Ws[j * CC + tid], wn = Wn[j * CC + tid];
        #pragma unroll
        for (int m = 0; m < 8; m++) acc[m] += as[m][j] * ws + ms[m][j] * wn;
    }
    #pragma unroll
    for (int m = 0; m < 8; m++) hs[m][tid] = fmaxf(acc[m], 0.f);
    __syncthreads();

    float acc2[8];
    #pragma unroll
    for (int m = 0; m < 8; m++) acc2[m] = bh[tid];
    for (int j = 0; j < CC; j++) {
        float w = Wh[j * OO + tid];
        #pragma unroll
        for (int m = 0; m < 8; m++) acc2[m] += hs[m][j] * w;
    }
    #pragma unroll
    for (int m = 0; m < 8; m++)
        out[(size_t)(n0 + m) * OO + tid] = acc2[m];
}

// ---------------------------------------------------------------------------
extern "C" void kernel_launch(void* const* d_in, const int* in_sizes, int n_in,
                              void* d_out, int out_size, void* d_ws, size_t ws_size,
                              hipStream_t stream)
{
    const float* x_raw      = (const float*)d_in[0];
    const float* eps        = (const float*)d_in[1];
    const float* col_logit  = (const float*)d_in[2];
    const float* type_logit = (const float*)d_in[3];
    const float* W_enc      = (const float*)d_in[4];
    const float* b_enc      = (const float*)d_in[5];
    const float* W_mu       = (const float*)d_in[6];
    const float* b_mu       = (const float*)d_in[7];
    const float* W_lv       = (const float*)d_in[8];
    const float* b_lv       = (const float*)d_in[9];
    const float* W_self1    = (const float*)d_in[10];
    const float* W_nbr1     = (const float*)d_in[11];
    const float* b1         = (const float*)d_in[12];
    const float* W_self2    = (const float*)d_in[13];
    const float* W_nbr2     = (const float*)d_in[14];
    const float* b2         = (const float*)d_in[15];
    const float* W_head     = (const float*)d_in[16];
    const float* b_head     = (const float*)d_in[17];
    float* out              = (float*)d_out;

    char* base = (char*)d_ws;
    size_t off = 0;
    auto alloc = [&](size_t bytes) { size_t o = off; off = (off + bytes + 255) & ~(size_t)255; return o; };

    const size_t MAT  = (size_t)NN * CC * 4;   // 8.39 MB

    float* z32    = (float*)(base + alloc(MAT));
    float* zn32   = (float*)(base + alloc(MAT));
    float* h1     = (float*)(base + alloc(MAT));
    unsigned short* znbF = (unsigned short*)(base + alloc((size_t)NN * CC * 2)); // 4.2 MB
    float* simmax = (float*)(base + alloc((size_t)NN * NT * 4));               // 16.8 MB
    float* Lrow   = (float*)(base + alloc((size_t)NN * 4));
    int*   ccnt   = (int*)(base + alloc((size_t)NN * 4));
    int*   ccol   = (int*)(base + alloc((size_t)NN * CAP * 4));                // 16.8 MB
    int*   nbr    = (int*)(base + alloc((size_t)NN * KP1 * 4));
    int*   deg    = (int*)(base + alloc((size_t)NN * 4));
    int*   rp     = (int*)(base + alloc((size_t)(NN + 1) * 4));
    int*   wp     = (int*)(base + alloc((size_t)NN * 4));
    int*   es     = (int*)(base + alloc((size_t)NN * KP1 * 4));

    k_pre<<<NN / 8, 128, 0, stream>>>(x_raw, eps, col_logit, type_logit,
                                      W_enc, b_enc, W_mu, b_mu, W_lv, b_lv,
                                      z32, zn32, znbF, deg, ccnt, nbr);

    const int NSUP = 64 * 64 + 64;             // 4160 supertile blocks
    k_simmax<<<NSUP, 512, 0, stream>>>(znbF, simmax);
    k_thresh<<<NN, 64, 0, stream>>>(simmax, Lrow);
    k_cand<<<NSUP, 512, 0, stream>>>(znbF, Lrow, ccnt, ccol);
    k_topk2<<<NN, 256, 0, stream>>>(ccnt, ccol, zn32, nbr, deg);

    k_scan<<<1, 256, 0, stream>>>(deg, rp, wp);
    int eb = (NN * KP1 + 255) / 256;
    k_fill<<<eb, 256, 0, stream>>>(nbr, wp, es);

    k_sage1<<<NN / 8, 128, 0, stream>>>(z32, rp, es, W_self1, W_nbr1, b1, h1);
    k_sage2h<<<NN / 8, 128, 0, stream>>>(h1, rp, es, W_self2, W_nbr2, b2,
                                         W_head, b_head, out);

    (void)in_sizes; (void)n_in; (void)out_size;
}